// Round 4
// baseline (427.774 us; speedup 1.0000x reference)
//
#include <hip/hip_runtime.h>
#include <hip/hip_bf16.h>
#include <math.h>

#define B_ 64
#define T_ 512
#define D_ 1024
#define M_ (B_*T_)   // 32768 rows of x flattened [B*T, D]

typedef unsigned short u16;
typedef __attribute__((ext_vector_type(8))) _Float16 f16x8;  // 8 fp16 in 4 VGPRs
typedef __attribute__((ext_vector_type(4))) float f32x4;

// fp32 -> fp16 RNE, bit pattern
__device__ __forceinline__ u16 f2h(float f) {
  union { _Float16 h; u16 u; } v;
  v.h = (_Float16)f;
  return v.u;
}

__device__ __forceinline__ float fast_tanh(float x) {
  // tanh(x) = 1 - 2/(exp(2x)+1); saturates correctly at +/-inf of expf
  return 1.0f - 2.0f / (__expf(2.0f * x) + 1.0f);
}

// async global->LDS, 16B per lane; LDS dest = wave-uniform base + lane*16
__device__ __forceinline__ void gll16(const void* g, void* l) {
  __builtin_amdgcn_global_load_lds(
      (const __attribute__((address_space(1))) unsigned int*)g,
      (__attribute__((address_space(3))) unsigned int*)l, 16, 0, 0);
}

// ---------------- K0a: convert x fp32 -> fp16 ----------------
__global__ __launch_bounds__(256) void cvt_x_kernel(const float4* __restrict__ x,
                                                    ushort4* __restrict__ xh, int n4) {
  int i = blockIdx.x * 256 + threadIdx.x;
  if (i < n4) {
    float4 v = x[i];
    ushort4 o;
    o.x = f2h(v.x); o.y = f2h(v.y); o.z = f2h(v.z); o.w = f2h(v.w);
    xh[i] = o;
  }
}

// ---------------- K0b: W [k,n] -> Wt [n,k] fp16 (LDS-tiled transpose) ----------------
__global__ __launch_bounds__(1024) void cvt_wt_kernel(const float* __restrict__ W,
                                                      u16* __restrict__ Wt) {
  __shared__ float tile[32][33];
  int tx = threadIdx.x & 31, ty = threadIdx.x >> 5;
  int n0 = blockIdx.x * 32, k0 = blockIdx.y * 32;
  tile[ty][tx] = W[(k0 + ty) * D_ + n0 + tx];
  __syncthreads();
  Wt[(n0 + ty) * D_ + k0 + tx] = f2h(tile[tx][ty]);
}

// ---------------- GEMM-BT core: 256x128 tile, 4 waves (wave tile 128x64), BK=32 -------
// LDS swizzle: row r, 16B chunk of logical k-pos c stored at in-row position
// (c + (r>>1)) & 3. Staging: LDS dest fixed (base+lane*16) so lane (pos p, row r)
// fetches global chunk (p - (r>>1)) & 3; read side adds the forward permutation.
// Banks become 2-way aliased (free, m136).
__device__ __forceinline__ void gemm_core(const u16* __restrict__ Abase,
                                          const u16* __restrict__ Bbase, int K,
                                          u16* As, u16* Bs, int tid, f32x4 acc[8][4]) {
  const int wave = tid >> 6, lane = tid & 63;
  // staging: A chunks wave*4..+3 (16 rows each), B chunks wave*2..+1
  const int swz_c = ((lane & 3) - ((lane >> 3) & 3)) & 3;   // global chunk to fetch
  const int rin = lane >> 2;                                 // row within 16-row chunk
  const u16* gA[4]; u16* lA[4];
#pragma unroll
  for (int j = 0; j < 4; j++) {
    int ci = wave * 4 + j;
    gA[j] = Abase + (long)(ci * 16 + rin) * K + swz_c * 8;
    lA[j] = As + ci * 512;
  }
  const u16* gB[2]; u16* lB[2];
#pragma unroll
  for (int j = 0; j < 2; j++) {
    int ci = wave * 2 + j;
    gB[j] = Bbase + (long)(ci * 16 + rin) * K + swz_c * 8;
    lB[j] = Bs + ci * 512;
  }

  const int wrow = (wave >> 1) * 128, wcol = (wave & 1) * 64;
  const int lm = lane & 15, qd = lane >> 4;
  const int swz_r = ((qd + (lm >> 1)) & 3) * 8;   // element offset of chunk qd in row
  const u16* ra = As + (wrow + lm) * 32 + swz_r;
  const u16* rb = Bs + (wcol + lm) * 32 + swz_r;

  for (int kt = 0; kt < K; kt += 32) {
#pragma unroll
    for (int j = 0; j < 4; j++) { gll16(gA[j], lA[j]); gA[j] += 32; }
#pragma unroll
    for (int j = 0; j < 2; j++) { gll16(gB[j], lB[j]); gB[j] += 32; }
    __syncthreads();
    f16x8 af[8], bfr[4];
#pragma unroll
    for (int i = 0; i < 8; i++) af[i] = *(const f16x8*)(ra + i * 512);
#pragma unroll
    for (int i = 0; i < 4; i++) bfr[i] = *(const f16x8*)(rb + i * 512);
#pragma unroll
    for (int mi = 0; mi < 8; mi++)
#pragma unroll
      for (int ni = 0; ni < 4; ni++)
        acc[mi][ni] = __builtin_amdgcn_mfma_f32_16x16x32_f16(af[mi], bfr[ni], acc[mi][ni], 0, 0, 0);
    __syncthreads();
  }
}

// ---------------- K1: xw = x @ W  (M=32768, N=1024, K=1024), out fp16 ----------------
__global__ __launch_bounds__(256, 2) void gemm1_kernel(const u16* __restrict__ xh,
                                                       const u16* __restrict__ wt,
                                                       u16* __restrict__ xw) {
  __shared__ u16 As[256 * 32], Bs[128 * 32];
  f32x4 acc[8][4] = {};
  const int tid = threadIdx.x;
  const long m0 = (long)blockIdx.y * 256;
  const long n0 = (long)blockIdx.x * 128;
  gemm_core(xh + m0 * D_, wt + n0 * D_, D_, As, Bs, tid, acc);

  const int wave = tid >> 6, lane = tid & 63;
  const int wrow = (wave >> 1) * 128, wcol = (wave & 1) * 64;
  const int lm = lane & 15, qd = lane >> 4;
#pragma unroll
  for (int mi = 0; mi < 8; mi++)
#pragma unroll
    for (int ni = 0; ni < 4; ni++) {
      long m = m0 + wrow + mi * 16 + qd * 4;   // C/D: row=(lane>>4)*4+reg
      long n = n0 + wcol + ni * 16 + lm;       //      col=lane&15
      u16* p = xw + m * D_ + n;
#pragma unroll
      for (int r = 0; r < 4; r++) p[(long)r * D_] = f2h(acc[mi][ni][r]);
    }
}

// ---------------- K2: eij tile + fused tanh*cv reduction -> partial scores ----------
// grid: bb(64) x tt(2: 256-row t-tiles) x st(4: 128-row s-tiles) = 512 blocks
// 8 partial planes: plane = st*2 + (wave&1)  (two waves per block share t rows but
// cover different 64-col s-halves -> MUST write distinct planes; round-3 raced here)
__global__ __launch_bounds__(256, 2) void gemm2_kernel(const u16* __restrict__ xw,
                                                       const u16* __restrict__ xh,
                                                       const float* __restrict__ bias,
                                                       const float* __restrict__ cv,
                                                       float* __restrict__ scores_part) {
  __shared__ u16 As[256 * 32], Bs[128 * 32];
  f32x4 acc[8][4] = {};
  const int bx = blockIdx.x;
  const int bb = bx >> 3, tt = (bx >> 2) & 1, st = bx & 3;
  const int tid = threadIdx.x;
  const long arow = (long)bb * T_ + tt * 256;
  const long brow = (long)bb * T_ + st * 128;
  gemm_core(xw + arow * D_, xh + brow * D_, D_, As, Bs, tid, acc);

  const int wave = tid >> 6, lane = tid & 63;
  const int wrow = (wave >> 1) * 128, wcol = (wave & 1) * 64;
  const int lm = lane & 15, qd = lane >> 4;
  float cvv[4], bv[4];
#pragma unroll
  for (int ni = 0; ni < 4; ni++) {
    int s = st * 128 + wcol + ni * 16 + lm;
    cvv[ni] = cv[s];
    bv[ni] = bias[s];
  }
  const int plane = st * 2 + (wave & 1);
  float* dst = scores_part + plane * (B_ * T_) + bb * T_ + tt * 256;
#pragma unroll
  for (int mi = 0; mi < 8; mi++) {
#pragma unroll
    for (int r = 0; r < 4; r++) {
      float p = 0.f;
#pragma unroll
      for (int ni = 0; ni < 4; ni++) p += fast_tanh(acc[mi][ni][r] + bv[ni]) * cvv[ni];
      // sum across the 16 cols held by this quad's lanes (lm bits 0..3)
      p += __shfl_xor(p, 1); p += __shfl_xor(p, 2);
      p += __shfl_xor(p, 4); p += __shfl_xor(p, 8);
      if (lm == 0) dst[wrow + mi * 16 + qd * 4 + r] = p;   // unique (plane,b,t) owner
    }
  }
}

// ---------------- K3: masked softmax over T per batch (sums 8 partials) ----------
__global__ __launch_bounds__(512) void softmax_kernel(const float* __restrict__ sp,
                                                      const unsigned char* __restrict__ m8,
                                                      float* __restrict__ a_out) {
  const int b = blockIdx.x, t = threadIdx.x;   // 512 threads = 8 waves
  __shared__ int nonz;
  __shared__ float redm[8], reds[8];
  if (t == 0) nonz = 0;
  __syncthreads();
  // detect int32-vs-uint8 bool storage
  unsigned char c = m8[t * 4 + 1] | m8[t * 4 + 2] | m8[t * 4 + 3];
  if (c) atomicOr(&nonz, 1);
  __syncthreads();
  const bool is_i32 = (nonz == 0);
  const int idx = b * T_ + t;
  const bool valid = is_i32 ? (m8[(long)idx * 4] != 0) : (m8[idx] != 0);

  float val = 0.f;
#pragma unroll
  for (int pl = 0; pl < 8; pl++) val += sp[pl * (B_ * T_) + idx];
  if (!valid) val = -INFINITY;
  float m = val;
#pragma unroll
  for (int o = 32; o > 0; o >>= 1) m = fmaxf(m, __shfl_xor(m, o));
  const int wv = t >> 6, ln = t & 63;
  if (ln == 0) redm[wv] = m;
  __syncthreads();
  float rowmax = redm[0];
#pragma unroll
  for (int i = 1; i < 8; i++) rowmax = fmaxf(rowmax, redm[i]);

  float e = valid ? expf(val - rowmax) : 0.f;
  float ssum = e;
#pragma unroll
  for (int o = 32; o > 0; o >>= 1) ssum += __shfl_xor(ssum, o);
  if (ln == 0) reds[wv] = ssum;
  __syncthreads();
  float tot = 0.f;
#pragma unroll
  for (int i = 0; i < 8; i++) tot += reds[i];
  a_out[idx] = e / tot;
}

// ---------------- K4: out[b,d] = sum_t a[b,t] * x[b,t,d] ----------------
__global__ __launch_bounds__(256) void wsum_kernel(const float* __restrict__ x,
                                                   const float* __restrict__ a,
                                                   float* __restrict__ out) {
  const int b = blockIdx.x, sl = blockIdx.y, tid = threadIdx.x; // grid (64, 8)
  const float4* xp = (const float4*)(x + (long)b * T_ * D_);
  float4 acc = make_float4(0.f, 0.f, 0.f, 0.f);
  for (int t = sl * 64; t < sl * 64 + 64; t++) {
    float av = a[b * T_ + t];
    float4 xv = xp[t * (D_ / 4) + tid];
    acc.x += av * xv.x; acc.y += av * xv.y; acc.z += av * xv.z; acc.w += av * xv.w;
  }
  float* op = out + (long)b * D_ + tid * 4;
  atomicAdd(op + 0, acc.x); atomicAdd(op + 1, acc.y);
  atomicAdd(op + 2, acc.z); atomicAdd(op + 3, acc.w);
}

extern "C" void kernel_launch(void* const* d_in, const int* in_sizes, int n_in,
                              void* d_out, int out_size, void* d_ws, size_t ws_size,
                              hipStream_t stream) {
  const float* x = (const float*)d_in[0];
  const unsigned char* mask = (const unsigned char*)d_in[1];
  const float* W = (const float*)d_in[2];
  const float* cv = (const float*)d_in[3];
  const float* bias = (const float*)d_in[4];

  float* out = (float*)d_out;                  // [B,D]
  float* a_out = out + (size_t)B_ * D_;        // [B,T]

  // workspace layout (130 MiB): scores_part (1 MiB, 8 planes) aliases wt (dead after gemm1)
  char* ws = (char*)d_ws;
  u16* xh = (u16*)(ws);                         // fp16 x    [M_, D_]  64 MiB
  u16* wt = (u16*)(ws + 67108864);              // fp16 W^T  [D_, D_]   2 MiB
  float* scores_part = (float*)(ws + 67108864); // fp32 [8][B_,T_] 1 MiB (aliases wt)
  u16* xw = (u16*)(ws + 69206016);              // fp16 x@W  [M_, D_]  64 MiB

  hipMemsetAsync(out, 0, (size_t)B_ * D_ * sizeof(float), stream);

  cvt_x_kernel<<<(M_ * D_ / 4 + 255) / 256, 256, 0, stream>>>((const float4*)x,
                                                              (ushort4*)xh, M_ * D_ / 4);
  cvt_wt_kernel<<<dim3(32, 32), 1024, 0, stream>>>(W, wt);
  gemm1_kernel<<<dim3(D_ / 128, M_ / 256), 256, 0, stream>>>(xh, wt, xw);
  gemm2_kernel<<<B_ * 8, 256, 0, stream>>>(xw, xh, bias, cv, scores_part);
  softmax_kernel<<<B_, 512, 0, stream>>>(scores_part, mask, a_out);
  wsum_kernel<<<dim3(B_, 8), 256, 0, stream>>>(x, a_out, out);
}

// Round 5
// 342.735 us; speedup vs baseline: 1.2481x; 1.2481x over previous
//
#include <hip/hip_runtime.h>
#include <hip/hip_bf16.h>
#include <math.h>

#define B_ 64
#define T_ 512
#define D_ 1024
#define M_ (B_*T_)   // 32768 rows of x flattened [B*T, D]

typedef unsigned short u16;
typedef __attribute__((ext_vector_type(8))) _Float16 f16x8;  // 8 fp16 in 4 VGPRs
typedef __attribute__((ext_vector_type(4))) float f32x4;

// fp32 -> fp16 RNE, bit pattern
__device__ __forceinline__ u16 f2h(float f) {
  union { _Float16 h; u16 u; } v;
  v.h = (_Float16)f;
  return v.u;
}

__device__ __forceinline__ float h2f(u16 u) {
  union { u16 u; _Float16 h; } v;
  v.u = u;
  return (float)v.h;
}

__device__ __forceinline__ float fast_tanh(float x) {
  // tanh(x) = 1 - 2/(exp(2x)+1); saturates correctly at +/-inf of expf
  return 1.0f - 2.0f / (__expf(2.0f * x) + 1.0f);
}

// async global->LDS, 16B per lane; LDS dest = wave-uniform base + lane*16
__device__ __forceinline__ void gll16(const void* g, void* l) {
  __builtin_amdgcn_global_load_lds(
      (const __attribute__((address_space(1))) unsigned int*)g,
      (__attribute__((address_space(3))) unsigned int*)l, 16, 0, 0);
}

// ---------------- K0a: convert x fp32 -> fp16 ----------------
__global__ __launch_bounds__(256) void cvt_x_kernel(const float4* __restrict__ x,
                                                    ushort4* __restrict__ xh, int n4) {
  int i = blockIdx.x * 256 + threadIdx.x;
  if (i < n4) {
    float4 v = x[i];
    ushort4 o;
    o.x = f2h(v.x); o.y = f2h(v.y); o.z = f2h(v.z); o.w = f2h(v.w);
    xh[i] = o;
  }
}

// ---------------- K0b: W [k,n] -> Wt [n,k] fp16 (LDS-tiled transpose) ----------------
__global__ __launch_bounds__(1024) void cvt_wt_kernel(const float* __restrict__ W,
                                                      u16* __restrict__ Wt) {
  __shared__ float tile[32][33];
  int tx = threadIdx.x & 31, ty = threadIdx.x >> 5;
  int n0 = blockIdx.x * 32, k0 = blockIdx.y * 32;
  tile[ty][tx] = W[(k0 + ty) * D_ + n0 + tx];
  __syncthreads();
  Wt[(n0 + ty) * D_ + k0 + tx] = f2h(tile[tx][ty]);
}

// LDS swizzle (both cores): row r, 16B chunk of logical k-pos c stored at in-row
// position (c + (r>>1)) & 3. Staging: lds dest fixed (base+lane*16) so lane
// (pos p, row r) fetches global chunk (p - (r>>1)) & 3; read side adds the forward
// permutation. Banks 2-way aliased = free (m136). Verified: conflicts 0 in round 4.

// ---------------- core A: 256x128 tile, wave tile 128x64, BK=32 (for gemm1) -------
__device__ __forceinline__ void gemm_core256(const u16* __restrict__ Abase,
                                             const u16* __restrict__ Bbase, int K,
                                             u16* As, u16* Bs, int tid, f32x4 acc[8][4]) {
  const int wave = tid >> 6, lane = tid & 63;
  const int swz_c = ((lane & 3) - ((lane >> 3) & 3)) & 3;   // global chunk to fetch
  const int rin = lane >> 2;                                 // row within 16-row chunk
  const u16* gA[4]; u16* lA[4];
#pragma unroll
  for (int j = 0; j < 4; j++) {
    int ci = wave * 4 + j;
    gA[j] = Abase + (long)(ci * 16 + rin) * K + swz_c * 8;
    lA[j] = As + ci * 512;
  }
  const u16* gB[2]; u16* lB[2];
#pragma unroll
  for (int j = 0; j < 2; j++) {
    int ci = wave * 2 + j;
    gB[j] = Bbase + (long)(ci * 16 + rin) * K + swz_c * 8;
    lB[j] = Bs + ci * 512;
  }

  const int wrow = (wave >> 1) * 128, wcol = (wave & 1) * 64;
  const int lm = lane & 15, qd = lane >> 4;
  const int swz_r = ((qd + (lm >> 1)) & 3) * 8;
  const u16* ra = As + (wrow + lm) * 32 + swz_r;
  const u16* rb = Bs + (wcol + lm) * 32 + swz_r;

  for (int kt = 0; kt < K; kt += 32) {
#pragma unroll
    for (int j = 0; j < 4; j++) { gll16(gA[j], lA[j]); gA[j] += 32; }
#pragma unroll
    for (int j = 0; j < 2; j++) { gll16(gB[j], lB[j]); gB[j] += 32; }
    __syncthreads();
    f16x8 af[8], bfr[4];
#pragma unroll
    for (int i = 0; i < 8; i++) af[i] = *(const f16x8*)(ra + i * 512);
#pragma unroll
    for (int i = 0; i < 4; i++) bfr[i] = *(const f16x8*)(rb + i * 512);
#pragma unroll
    for (int mi = 0; mi < 8; mi++)
#pragma unroll
      for (int ni = 0; ni < 4; ni++)
        acc[mi][ni] = __builtin_amdgcn_mfma_f32_16x16x32_f16(af[mi], bfr[ni], acc[mi][ni], 0, 0, 0);
    __syncthreads();
  }
}

// ---------------- core B: 128x128 tile, wave tile 64x64, BK=32 (for gemm2) -------
__device__ __forceinline__ void gemm_core128(const u16* __restrict__ Abase,
                                             const u16* __restrict__ Bbase, int K,
                                             u16* As, u16* Bs, int tid, f32x4 acc[4][4]) {
  const int wave = tid >> 6, lane = tid & 63;
  const int swz_c = ((lane & 3) - ((lane >> 3) & 3)) & 3;
  const int rin = lane >> 2;
  const u16* gA[2]; u16* lA[2];
  const u16* gB[2]; u16* lB[2];
#pragma unroll
  for (int j = 0; j < 2; j++) {
    int ci = wave * 2 + j;
    gA[j] = Abase + (long)(ci * 16 + rin) * K + swz_c * 8;
    lA[j] = As + ci * 512;
    gB[j] = Bbase + (long)(ci * 16 + rin) * K + swz_c * 8;
    lB[j] = Bs + ci * 512;
  }
  const int wrow = (wave >> 1) * 64, wcol = (wave & 1) * 64;
  const int lm = lane & 15, qd = lane >> 4;
  const int swz_r = ((qd + (lm >> 1)) & 3) * 8;
  const u16* ra = As + (wrow + lm) * 32 + swz_r;
  const u16* rb = Bs + (wcol + lm) * 32 + swz_r;

  for (int kt = 0; kt < K; kt += 32) {
#pragma unroll
    for (int j = 0; j < 2; j++) {
      gll16(gA[j], lA[j]); gA[j] += 32;
      gll16(gB[j], lB[j]); gB[j] += 32;
    }
    __syncthreads();
    f16x8 af[4], bfr[4];
#pragma unroll
    for (int i = 0; i < 4; i++) {
      af[i] = *(const f16x8*)(ra + i * 512);
      bfr[i] = *(const f16x8*)(rb + i * 512);
    }
#pragma unroll
    for (int mi = 0; mi < 4; mi++)
#pragma unroll
      for (int ni = 0; ni < 4; ni++)
        acc[mi][ni] = __builtin_amdgcn_mfma_f32_16x16x32_f16(af[mi], bfr[ni], acc[mi][ni], 0, 0, 0);
    __syncthreads();
  }
}

// ---------------- K1: xw = x @ W  (M=32768, N=1024, K=1024), out fp16 ----------------
// XCD grouping: bx&7 = XCD; the 8 n-tiles of one m-stripe share an XCD so the
// A-stripe (512 KB) is fetched into that L2 once.
__global__ __launch_bounds__(256, 2) void gemm1_kernel(const u16* __restrict__ xh,
                                                       const u16* __restrict__ wt,
                                                       u16* __restrict__ xw) {
  __shared__ u16 As[256 * 32], Bs[128 * 32];
  f32x4 acc[8][4] = {};
  const int tid = threadIdx.x;
  const int bx = blockIdx.x;                 // 1024 blocks
  const int xcd = bx & 7, j = bx >> 3;       // j in [0,128)
  const int mt = xcd * 16 + (j >> 3);        // 128 m-tiles
  const int nt = j & 7;                      // 8 n-tiles
  const long m0 = (long)mt * 256;
  const long n0 = (long)nt * 128;
  gemm_core256(xh + m0 * D_, wt + n0 * D_, D_, As, Bs, tid, acc);

  const int wave = tid >> 6, lane = tid & 63;
  const int wrow = (wave >> 1) * 128, wcol = (wave & 1) * 64;
  const int lm = lane & 15, qd = lane >> 4;
#pragma unroll
  for (int mi = 0; mi < 8; mi++)
#pragma unroll
    for (int ni = 0; ni < 4; ni++) {
      long m = m0 + wrow + mi * 16 + qd * 4;   // C/D: row=(lane>>4)*4+reg
      long n = n0 + wcol + ni * 16 + lm;       //      col=lane&15
      u16* p = xw + m * D_ + n;
#pragma unroll
      for (int r = 0; r < 4; r++) p[(long)r * D_] = f2h(acc[mi][ni][r]);
    }
}

// ---------------- K2: eij 128x128 tile + fused tanh*cv reduction -> partial scores ----
// 1024 blocks (4/CU). XCD grouping: the 16 tiles of one batch share an XCD with
// consecutive dispatch order -> batch working set (2 MB) fits the 4 MiB XCD-L2.
// 8 partial planes: plane = st*2 + (wave&1) (waves sharing t-rows cover different
// 64-col s-halves -> distinct planes; fixed race from round 3).
__global__ __launch_bounds__(256, 4) void gemm2_kernel(const u16* __restrict__ xw,
                                                       const u16* __restrict__ xh,
                                                       const float* __restrict__ bias,
                                                       const float* __restrict__ cv,
                                                       float* __restrict__ scores_part) {
  __shared__ u16 As[128 * 32], Bs[128 * 32];
  f32x4 acc[4][4] = {};
  const int bx = blockIdx.x;
  const int xcd = bx & 7, j = bx >> 3;       // j in [0,128)
  const int bb = xcd * 8 + (j >> 4);         // 64 batches, 8 per XCD
  const int tile = j & 15;                   // 16 tiles per batch, consecutive j
  const int tt = tile >> 2, st = tile & 3;
  const int tid = threadIdx.x;
  const long arow = (long)bb * T_ + tt * 128;
  const long brow = (long)bb * T_ + st * 128;
  gemm_core128(xw + arow * D_, xh + brow * D_, D_, As, Bs, tid, acc);

  const int wave = tid >> 6, lane = tid & 63;
  const int wrow = (wave >> 1) * 64, wcol = (wave & 1) * 64;
  const int lm = lane & 15, qd = lane >> 4;
  float cvv[4], bv[4];
#pragma unroll
  for (int ni = 0; ni < 4; ni++) {
    int s = st * 128 + wcol + ni * 16 + lm;
    cvv[ni] = cv[s];
    bv[ni] = bias[s];
  }
  const int plane = st * 2 + (wave & 1);
  float* dst = scores_part + plane * (B_ * T_) + bb * T_ + tt * 128;
#pragma unroll
  for (int mi = 0; mi < 4; mi++) {
#pragma unroll
    for (int r = 0; r < 4; r++) {
      float p = 0.f;
#pragma unroll
      for (int ni = 0; ni < 4; ni++) p += fast_tanh(acc[mi][ni][r] + bv[ni]) * cvv[ni];
      // sum across the 16 cols held by this quad's lanes (lm bits 0..3)
      p += __shfl_xor(p, 1); p += __shfl_xor(p, 2);
      p += __shfl_xor(p, 4); p += __shfl_xor(p, 8);
      if (lm == 0) dst[wrow + mi * 16 + qd * 4 + r] = p;   // unique (plane,b,t) owner
    }
  }
}

// ---------------- K3: masked softmax over T per batch (sums 8 partials) ----------
__global__ __launch_bounds__(512) void softmax_kernel(const float* __restrict__ sp,
                                                      const unsigned char* __restrict__ m8,
                                                      float* __restrict__ a_out) {
  const int b = blockIdx.x, t = threadIdx.x;   // 512 threads = 8 waves
  __shared__ int nonz;
  __shared__ float redm[8], reds[8];
  if (t == 0) nonz = 0;
  __syncthreads();
  // detect int32-vs-uint8 bool storage
  unsigned char c = m8[t * 4 + 1] | m8[t * 4 + 2] | m8[t * 4 + 3];
  if (c) atomicOr(&nonz, 1);
  __syncthreads();
  const bool is_i32 = (nonz == 0);
  const int idx = b * T_ + t;
  const bool valid = is_i32 ? (m8[(long)idx * 4] != 0) : (m8[idx] != 0);

  float val = 0.f;
#pragma unroll
  for (int pl = 0; pl < 8; pl++) val += sp[pl * (B_ * T_) + idx];
  if (!valid) val = -INFINITY;
  float m = val;
#pragma unroll
  for (int o = 32; o > 0; o >>= 1) m = fmaxf(m, __shfl_xor(m, o));
  const int wv = t >> 6, ln = t & 63;
  if (ln == 0) redm[wv] = m;
  __syncthreads();
  float rowmax = redm[0];
#pragma unroll
  for (int i = 1; i < 8; i++) rowmax = fmaxf(rowmax, redm[i]);

  float e = valid ? expf(val - rowmax) : 0.f;
  float ssum = e;
#pragma unroll
  for (int o = 32; o > 0; o >>= 1) ssum += __shfl_xor(ssum, o);
  if (ln == 0) reds[wv] = ssum;
  __syncthreads();
  float tot = 0.f;
#pragma unroll
  for (int i = 0; i < 8; i++) tot += reds[i];
  a_out[idx] = e / tot;
}

// ---------------- K4: out[b,d] = sum_t a[b,t] * xh[b,t,d]  (atomic-free) -------
// grid (64,4) x 256 thr: block owns (b, d-slice of 256). Plain stores, no memset.
__global__ __launch_bounds__(256) void wsum_kernel(const u16* __restrict__ xh,
                                                   const float* __restrict__ a,
                                                   float* __restrict__ out) {
  const int b = blockIdx.x, sl = blockIdx.y, tid = threadIdx.x;
  const int d = sl * 256 + tid;
  const u16* xp = xh + (long)b * T_ * D_ + d;
  const float* ap = a + b * T_;
  float acc = 0.f;
  for (int t = 0; t < T_; t++)
    acc += ap[t] * h2f(xp[(long)t * D_]);
  out[(long)b * D_ + d] = acc;
}

extern "C" void kernel_launch(void* const* d_in, const int* in_sizes, int n_in,
                              void* d_out, int out_size, void* d_ws, size_t ws_size,
                              hipStream_t stream) {
  const float* x = (const float*)d_in[0];
  const unsigned char* mask = (const unsigned char*)d_in[1];
  const float* W = (const float*)d_in[2];
  const float* cv = (const float*)d_in[3];
  const float* bias = (const float*)d_in[4];

  float* out = (float*)d_out;                  // [B,D]
  float* a_out = out + (size_t)B_ * D_;        // [B,T]

  // workspace layout (130 MiB): scores_part (1 MiB, 8 planes) aliases wt (dead after gemm1)
  char* ws = (char*)d_ws;
  u16* xh = (u16*)(ws);                         // fp16 x    [M_, D_]  64 MiB
  u16* wt = (u16*)(ws + 67108864);              // fp16 W^T  [D_, D_]   2 MiB
  float* scores_part = (float*)(ws + 67108864); // fp32 [8][B_,T_] 1 MiB (aliases wt)
  u16* xw = (u16*)(ws + 69206016);              // fp16 x@W  [M_, D_]  64 MiB

  cvt_x_kernel<<<(M_ * D_ / 4 + 255) / 256, 256, 0, stream>>>((const float4*)x,
                                                              (ushort4*)xh, M_ * D_ / 4);
  cvt_wt_kernel<<<dim3(32, 32), 1024, 0, stream>>>(W, wt);
  gemm1_kernel<<<1024, 256, 0, stream>>>(xh, wt, xw);
  gemm2_kernel<<<1024, 256, 0, stream>>>(xw, xh, bias, cv, scores_part);
  softmax_kernel<<<B_, 512, 0, stream>>>(scores_part, mask, a_out);
  wsum_kernel<<<dim3(B_, 4), 256, 0, stream>>>(xh, a_out, out);
}